// Round 2
// baseline (1828.710 us; speedup 1.0000x reference)
//
#include <hip/hip_runtime.h>
#include <hip/hip_bf16.h>

// MultiLoRALinear: out[b,s,o] = x@W.T + bias + (x @ A[idx[b]]) @ B[idx[b]]
// M = 8*2048 = 16384, K = 4096, N = 4096, rank 16, ALPHA = 1.
//
// R1 changes vs R0:
//  - GEMM LDS XOR-swizzle (p = s ^ (row&7)) with pre-swizzled global source
//    (global_load_lds writes linearly -> inverse perm on source, swizzle on read).
//    Kills the 16-way bank conflict (2.0e8 extra cycles in R0).
//  - __launch_bounds__(256,4): 4 blocks/CU (VGPR 128, 32KiB LDS allow it).
//  - fused_xcvt_inter: reads x fp32 once, writes bf16 x + fp32 inter; 16 rows
//    share A-slot loads (A L2 traffic 4.3GB -> 268MB). Replaces cvt_x + old inter.

#define M_TOT 16384
#define K_TOT 4096
#define N_TOT 4096
#define RANK 16

typedef __attribute__((ext_vector_type(8))) short bf16x8;
typedef __attribute__((ext_vector_type(4))) float f32x4;

// ---------------- fp32 -> bf16 (round-to-nearest-even) ----------------
__device__ __forceinline__ unsigned short f2bf(float f) {
  unsigned int u = __builtin_bit_cast(unsigned int, f);
  u += 0x7fffu + ((u >> 16) & 1u);
  return (unsigned short)(u >> 16);
}

__global__ void cvt_bf16_kernel(const float* __restrict__ src,
                                unsigned short* __restrict__ dst, int n4) {
  int i = blockIdx.x * blockDim.x + threadIdx.x;
  const int stride = gridDim.x * blockDim.x;
  for (; i < n4; i += stride) {
    const float4 v = reinterpret_cast<const float4*>(src)[i];
    ushort4 o;
    o.x = f2bf(v.x); o.y = f2bf(v.y); o.z = f2bf(v.z); o.w = f2bf(v.w);
    reinterpret_cast<ushort4*>(dst)[i] = o;
  }
}

// ------- fused: xb = bf16(x); inter = x @ A[slot]  (16 rows per block) -------
// block: 256 threads; row = r0 + (tid>>4), 16 k-parts per row (p = tid&15).
// Thread covers k = p*4 + 64*i, i=0..63 (float4 chunks). A reads are shared:
// 16 lanes with the same p read identical A addresses (broadcast transaction).
__global__ __launch_bounds__(256) void fused_xcvt_inter_kernel(
    const float* __restrict__ x,
    const float* __restrict__ loraA,
    const int* __restrict__ idx,
    unsigned short* __restrict__ xb,
    float* __restrict__ inter) {
  const int tid = threadIdx.x;
  const int row = blockIdx.x * 16 + (tid >> 4);
  const int p = tid & 15;
  const int slot = idx[row >> 11];
  const float* __restrict__ A = loraA + (size_t)slot * K_TOT * RANK;
  const float* __restrict__ xr = x + (size_t)row * K_TOT;
  unsigned short* __restrict__ xbr = xb + (size_t)row * K_TOT;

  float acc[RANK];
#pragma unroll
  for (int r = 0; r < RANK; ++r) acc[r] = 0.f;

  for (int i = 0; i < 64; ++i) {
    const int k = p * 4 + i * 64;
    const float4 xv = *reinterpret_cast<const float4*>(xr + k);
    // write bf16 side-output
    ushort4 o;
    o.x = f2bf(xv.x); o.y = f2bf(xv.y); o.z = f2bf(xv.z); o.w = f2bf(xv.w);
    *reinterpret_cast<ushort4*>(xbr + k) = o;
    // accumulate inter: 4 A-rows of 16
    const float xe[4] = {xv.x, xv.y, xv.z, xv.w};
#pragma unroll
    for (int j = 0; j < 4; ++j) {
      const float4* Ar = reinterpret_cast<const float4*>(A + (size_t)(k + j) * RANK);
      const float4 a0 = Ar[0], a1 = Ar[1], a2 = Ar[2], a3 = Ar[3];
      const float xs = xe[j];
      acc[0]  += xs * a0.x;  acc[1]  += xs * a0.y;  acc[2]  += xs * a0.z;  acc[3]  += xs * a0.w;
      acc[4]  += xs * a1.x;  acc[5]  += xs * a1.y;  acc[6]  += xs * a1.z;  acc[7]  += xs * a1.w;
      acc[8]  += xs * a2.x;  acc[9]  += xs * a2.y;  acc[10] += xs * a2.z;  acc[11] += xs * a2.w;
      acc[12] += xs * a3.x;  acc[13] += xs * a3.y;  acc[14] += xs * a3.z;  acc[15] += xs * a3.w;
    }
  }
  // reduce over the 16 k-parts (consecutive lanes within 16-lane groups)
#pragma unroll
  for (int r = 0; r < RANK; ++r) {
    float v = acc[r];
    v += __shfl_xor(v, 1);
    v += __shfl_xor(v, 2);
    v += __shfl_xor(v, 4);
    v += __shfl_xor(v, 8);
    acc[r] = v;
  }
  if (p == 0) {
    float4* op = reinterpret_cast<float4*>(inter + (size_t)row * RANK);
    op[0] = make_float4(acc[0], acc[1], acc[2], acc[3]);
    op[1] = make_float4(acc[4], acc[5], acc[6], acc[7]);
    op[2] = make_float4(acc[8], acc[9], acc[10], acc[11]);
    op[3] = make_float4(acc[12], acc[13], acc[14], acc[15]);
  }
}

// ---------------- fused GEMM ----------------
// 128x128 tile, BK=64, 4 waves (2x2), 4x4 fragments of 16x16x32 per wave.
// LDS tile [128 rows][8 slots of 16B]; physical slot p = s ^ (row&7).
#define BM 128
#define BN 128
#define BK 64

__device__ __forceinline__ void gload16(const void* g, void* l) {
  __builtin_amdgcn_global_load_lds(
      (const __attribute__((address_space(1))) unsigned int*)g,
      (__attribute__((address_space(3))) unsigned int*)l, 16, 0, 0);
}

__global__ __launch_bounds__(256, 4) void gemm_fused_kernel(
    const unsigned short* __restrict__ xb,   // [M_TOT][K] bf16
    const unsigned short* __restrict__ wb,   // [N_TOT][K] bf16
    const float* __restrict__ bias,          // [N]
    const float* __restrict__ inter,         // [M_TOT][RANK] fp32
    const float* __restrict__ loraB,         // [32][RANK][N] fp32
    const int* __restrict__ idx,             // [8]
    float* __restrict__ out) {               // [M_TOT][N] fp32
  __shared__ unsigned short As[BM * BK];     // 16 KiB
  __shared__ unsigned short Bs[BN * BK];     // 16 KiB

  const int tid = threadIdx.x;
  const int lane = tid & 63;
  const int wv = tid >> 6;
  const int wr = wv >> 1, wc = wv & 1;       // 2x2 wave grid

  const int bid = blockIdx.x;
  const int bm = bid >> 5;                   // 0..127
  const int bn = bid & 31;                   // 0..31
  const int m0 = bm * BM;
  const int n0 = bn * BN;

  f32x4 acc[4][4];
#pragma unroll
  for (int i = 0; i < 4; ++i)
#pragma unroll
    for (int j = 0; j < 4; ++j) acc[i][j] = (f32x4){0.f, 0.f, 0.f, 0.f};

  // staging: chunk c covers physical LDS (row=c>>3, slot=c&7).
  // source column is the INVERSE swizzle: s = (c&7) ^ ((c>>3)&7).
  const unsigned short* gA[4];
  const unsigned short* gB[4];
  int loff[4];
#pragma unroll
  for (int i = 0; i < 4; ++i) {
    const int c = (wv * 4 + i) * 64 + lane;  // 0..1023
    const int row = c >> 3;
    const int scol = ((c & 7) ^ (row & 7)) << 3;  // bf16 elements within row
    gA[i] = xb + (size_t)(m0 + row) * K_TOT + scol;
    gB[i] = wb + (size_t)(n0 + row) * K_TOT + scol;
    loff[i] = (wv * 4 + i) * 512;            // wave-uniform LDS base (elements)
  }

  // LDS fragment read byte-offsets, swizzled: byte = r*128 + ((s^(r&7))<<4)
  int aoff0[4], aoff1[4], boff0[4], boff1[4];
  const int s0 = lane >> 4;                  // logical 16B slot at kk=0
#pragma unroll
  for (int i = 0; i < 4; ++i) {
    const int ra = wr * 64 + i * 16 + (lane & 15);
    const int rb = wc * 64 + i * 16 + (lane & 15);
    aoff0[i] = ra * 128 + ((s0 ^ (ra & 7)) << 4);
    aoff1[i] = ra * 128 + (((s0 + 4) ^ (ra & 7)) << 4);
    boff0[i] = rb * 128 + ((s0 ^ (rb & 7)) << 4);
    boff1[i] = rb * 128 + (((s0 + 4) ^ (rb & 7)) << 4);
  }
  const char* Asb = reinterpret_cast<const char*>(As);
  const char* Bsb = reinterpret_cast<const char*>(Bs);

  for (int kt = 0; kt < K_TOT; kt += BK) {
#pragma unroll
    for (int i = 0; i < 4; ++i) {
      gload16(gA[i] + kt, As + loff[i]);
      gload16(gB[i] + kt, Bs + loff[i]);
    }
    __syncthreads();  // vmcnt(0): staged data visible

    {
      bf16x8 af[4], bfr[4];
#pragma unroll
      for (int mi = 0; mi < 4; ++mi)
        af[mi] = *reinterpret_cast<const bf16x8*>(Asb + aoff0[mi]);
#pragma unroll
      for (int ni = 0; ni < 4; ++ni)
        bfr[ni] = *reinterpret_cast<const bf16x8*>(Bsb + boff0[ni]);
#pragma unroll
      for (int mi = 0; mi < 4; ++mi)
#pragma unroll
        for (int ni = 0; ni < 4; ++ni)
          acc[mi][ni] = __builtin_amdgcn_mfma_f32_16x16x32_bf16(
              af[mi], bfr[ni], acc[mi][ni], 0, 0, 0);
#pragma unroll
      for (int mi = 0; mi < 4; ++mi)
        af[mi] = *reinterpret_cast<const bf16x8*>(Asb + aoff1[mi]);
#pragma unroll
      for (int ni = 0; ni < 4; ++ni)
        bfr[ni] = *reinterpret_cast<const bf16x8*>(Bsb + boff1[ni]);
#pragma unroll
      for (int mi = 0; mi < 4; ++mi)
#pragma unroll
        for (int ni = 0; ni < 4; ++ni)
          acc[mi][ni] = __builtin_amdgcn_mfma_f32_16x16x32_bf16(
              af[mi], bfr[ni], acc[mi][ni], 0, 0, 0);
    }
    __syncthreads();  // all waves done reading before next stage
  }

  // ---------------- epilogue: + bias + inter @ B[slot] ----------------
  const int slot = idx[m0 >> 11];            // uniform per block (128 | 2048)
  const float* __restrict__ Bmat = loraB + (size_t)slot * RANK * N_TOT;

#pragma unroll
  for (int ni = 0; ni < 4; ++ni) {
    const int gn = n0 + wc * 64 + ni * 16 + (lane & 15);
    const float bv = bias[gn];
    float bc[RANK];
#pragma unroll
    for (int q = 0; q < RANK; ++q) bc[q] = Bmat[q * N_TOT + gn];
#pragma unroll
    for (int mi = 0; mi < 4; ++mi) {
      const int gmb = m0 + wr * 64 + mi * 16 + ((lane >> 4) << 2);
#pragma unroll
      for (int r = 0; r < 4; ++r) {
        const int gm = gmb + r;
        const float* __restrict__ iv = inter + (size_t)gm * RANK;
        float lora = 0.f;
#pragma unroll
        for (int q = 0; q < RANK; ++q) lora += iv[q] * bc[q];
        out[(size_t)gm * N_TOT + gn] = acc[mi][ni][r] + bv + lora;
      }
    }
  }
}

// ---------------- host launcher ----------------
extern "C" void kernel_launch(void* const* d_in, const int* in_sizes, int n_in,
                              void* d_out, int out_size, void* d_ws, size_t ws_size,
                              hipStream_t stream) {
  const float* x     = (const float*)d_in[0];  // [8,2048,4096]
  const float* w     = (const float*)d_in[1];  // [4096,4096]
  const float* bias  = (const float*)d_in[2];  // [4096]
  const float* loraA = (const float*)d_in[3];  // [32,4096,16]
  const float* loraB = (const float*)d_in[4];  // [32,16,4096]
  const int*   idx   = (const int*)d_in[5];    // [8]
  float* out = (float*)d_out;

  char* ws = (char*)d_ws;
  unsigned short* xb = (unsigned short*)ws;                       // 134,217,728 B
  unsigned short* wbuf = (unsigned short*)(ws + 134217728);       //  33,554,432 B
  float* inter = (float*)(ws + 134217728 + 33554432);             //   1,048,576 B

  fused_xcvt_inter_kernel<<<M_TOT / 16, 256, 0, stream>>>(x, loraA, idx, xb, inter);
  cvt_bf16_kernel<<<1024, 256, 0, stream>>>(w, wbuf, N_TOT * K_TOT / 4);
  gemm_fused_kernel<<<(M_TOT / BM) * (N_TOT / BN), 256, 0, stream>>>(
      xb, wbuf, bias, inter, loraB, idx, out);
}

// Round 3
// 1407.515 us; speedup vs baseline: 1.2992x; 1.2992x over previous
//
#include <hip/hip_runtime.h>
#include <hip/hip_bf16.h>

// MultiLoRALinear: out[b,s,o] = x@W.T + bias + (x @ A[idx[b]]) @ B[idx[b]]
// M = 8*2048 = 16384, K = 4096, N = 4096, rank 16, ALPHA = 1.
//
// R2 changes vs R1:
//  - REVERT __launch_bounds__(256,4) -> (256,2). R1 evidence: VGPR_Count 64,
//    WRITE_SIZE 348MB->1.78GB, FETCH +1.2GB = accumulator spill to scratch.
//    The register budget (VGPR+AGPR unified) needs ~200 regs/thread; 4
//    blocks/CU caps it at 128. Occupancy was bought with registers we need.
//  - KEEP the LDS XOR-swizzle (SQ_LDS_BANK_CONFLICT 2.0e8 -> 0, verified).
//  - KEEP fused_xcvt_inter pre-pass.

#define M_TOT 16384
#define K_TOT 4096
#define N_TOT 4096
#define RANK 16

typedef __attribute__((ext_vector_type(8))) short bf16x8;
typedef __attribute__((ext_vector_type(4))) float f32x4;

// ---------------- fp32 -> bf16 (round-to-nearest-even) ----------------
__device__ __forceinline__ unsigned short f2bf(float f) {
  unsigned int u = __builtin_bit_cast(unsigned int, f);
  u += 0x7fffu + ((u >> 16) & 1u);
  return (unsigned short)(u >> 16);
}

__global__ void cvt_bf16_kernel(const float* __restrict__ src,
                                unsigned short* __restrict__ dst, int n4) {
  int i = blockIdx.x * blockDim.x + threadIdx.x;
  const int stride = gridDim.x * blockDim.x;
  for (; i < n4; i += stride) {
    const float4 v = reinterpret_cast<const float4*>(src)[i];
    ushort4 o;
    o.x = f2bf(v.x); o.y = f2bf(v.y); o.z = f2bf(v.z); o.w = f2bf(v.w);
    reinterpret_cast<ushort4*>(dst)[i] = o;
  }
}

// ------- fused: xb = bf16(x); inter = x @ A[slot]  (16 rows per block) -------
__global__ __launch_bounds__(256) void fused_xcvt_inter_kernel(
    const float* __restrict__ x,
    const float* __restrict__ loraA,
    const int* __restrict__ idx,
    unsigned short* __restrict__ xb,
    float* __restrict__ inter) {
  const int tid = threadIdx.x;
  const int row = blockIdx.x * 16 + (tid >> 4);
  const int p = tid & 15;
  const int slot = idx[row >> 11];
  const float* __restrict__ A = loraA + (size_t)slot * K_TOT * RANK;
  const float* __restrict__ xr = x + (size_t)row * K_TOT;
  unsigned short* __restrict__ xbr = xb + (size_t)row * K_TOT;

  float acc[RANK];
#pragma unroll
  for (int r = 0; r < RANK; ++r) acc[r] = 0.f;

  for (int i = 0; i < 64; ++i) {
    const int k = p * 4 + i * 64;
    const float4 xv = *reinterpret_cast<const float4*>(xr + k);
    ushort4 o;
    o.x = f2bf(xv.x); o.y = f2bf(xv.y); o.z = f2bf(xv.z); o.w = f2bf(xv.w);
    *reinterpret_cast<ushort4*>(xbr + k) = o;
    const float xe[4] = {xv.x, xv.y, xv.z, xv.w};
#pragma unroll
    for (int j = 0; j < 4; ++j) {
      const float4* Ar = reinterpret_cast<const float4*>(A + (size_t)(k + j) * RANK);
      const float4 a0 = Ar[0], a1 = Ar[1], a2 = Ar[2], a3 = Ar[3];
      const float xs = xe[j];
      acc[0]  += xs * a0.x;  acc[1]  += xs * a0.y;  acc[2]  += xs * a0.z;  acc[3]  += xs * a0.w;
      acc[4]  += xs * a1.x;  acc[5]  += xs * a1.y;  acc[6]  += xs * a1.z;  acc[7]  += xs * a1.w;
      acc[8]  += xs * a2.x;  acc[9]  += xs * a2.y;  acc[10] += xs * a2.z;  acc[11] += xs * a2.w;
      acc[12] += xs * a3.x;  acc[13] += xs * a3.y;  acc[14] += xs * a3.z;  acc[15] += xs * a3.w;
    }
  }
#pragma unroll
  for (int r = 0; r < RANK; ++r) {
    float v = acc[r];
    v += __shfl_xor(v, 1);
    v += __shfl_xor(v, 2);
    v += __shfl_xor(v, 4);
    v += __shfl_xor(v, 8);
    acc[r] = v;
  }
  if (p == 0) {
    float4* op = reinterpret_cast<float4*>(inter + (size_t)row * RANK);
    op[0] = make_float4(acc[0], acc[1], acc[2], acc[3]);
    op[1] = make_float4(acc[4], acc[5], acc[6], acc[7]);
    op[2] = make_float4(acc[8], acc[9], acc[10], acc[11]);
    op[3] = make_float4(acc[12], acc[13], acc[14], acc[15]);
  }
}

// ---------------- fused GEMM ----------------
// 128x128 tile, BK=64, 4 waves (2x2), 4x4 fragments of 16x16x32 per wave.
// LDS tile [128 rows][8 slots of 16B]; physical slot p = s ^ (row&7).
#define BM 128
#define BN 128
#define BK 64

__device__ __forceinline__ void gload16(const void* g, void* l) {
  __builtin_amdgcn_global_load_lds(
      (const __attribute__((address_space(1))) unsigned int*)g,
      (__attribute__((address_space(3))) unsigned int*)l, 16, 0, 0);
}

__global__ __launch_bounds__(256, 2) void gemm_fused_kernel(
    const unsigned short* __restrict__ xb,   // [M_TOT][K] bf16
    const unsigned short* __restrict__ wb,   // [N_TOT][K] bf16
    const float* __restrict__ bias,          // [N]
    const float* __restrict__ inter,         // [M_TOT][RANK] fp32
    const float* __restrict__ loraB,         // [32][RANK][N] fp32
    const int* __restrict__ idx,             // [8]
    float* __restrict__ out) {               // [M_TOT][N] fp32
  __shared__ unsigned short As[BM * BK];     // 16 KiB
  __shared__ unsigned short Bs[BN * BK];     // 16 KiB

  const int tid = threadIdx.x;
  const int lane = tid & 63;
  const int wv = tid >> 6;
  const int wr = wv >> 1, wc = wv & 1;       // 2x2 wave grid

  const int bid = blockIdx.x;
  const int bm = bid >> 5;                   // 0..127
  const int bn = bid & 31;                   // 0..31
  const int m0 = bm * BM;
  const int n0 = bn * BN;

  f32x4 acc[4][4];
#pragma unroll
  for (int i = 0; i < 4; ++i)
#pragma unroll
    for (int j = 0; j < 4; ++j) acc[i][j] = (f32x4){0.f, 0.f, 0.f, 0.f};

  // staging: chunk c covers physical LDS (row=c>>3, slot=c&7).
  // source column is the INVERSE swizzle: s = (c&7) ^ ((c>>3)&7).
  const unsigned short* gA[4];
  const unsigned short* gB[4];
  int loff[4];
#pragma unroll
  for (int i = 0; i < 4; ++i) {
    const int c = (wv * 4 + i) * 64 + lane;  // 0..1023
    const int row = c >> 3;
    const int scol = ((c & 7) ^ (row & 7)) << 3;  // bf16 elements within row
    gA[i] = xb + (size_t)(m0 + row) * K_TOT + scol;
    gB[i] = wb + (size_t)(n0 + row) * K_TOT + scol;
    loff[i] = (wv * 4 + i) * 512;            // wave-uniform LDS base (elements)
  }

  // LDS fragment read byte-offsets, swizzled: byte = r*128 + ((s^(r&7))<<4)
  int aoff0[4], aoff1[4], boff0[4], boff1[4];
  const int s0 = lane >> 4;                  // logical 16B slot at kk=0
#pragma unroll
  for (int i = 0; i < 4; ++i) {
    const int ra = wr * 64 + i * 16 + (lane & 15);
    const int rb = wc * 64 + i * 16 + (lane & 15);
    aoff0[i] = ra * 128 + ((s0 ^ (ra & 7)) << 4);
    aoff1[i] = ra * 128 + (((s0 + 4) ^ (ra & 7)) << 4);
    boff0[i] = rb * 128 + ((s0 ^ (rb & 7)) << 4);
    boff1[i] = rb * 128 + (((s0 + 4) ^ (rb & 7)) << 4);
  }
  const char* Asb = reinterpret_cast<const char*>(As);
  const char* Bsb = reinterpret_cast<const char*>(Bs);

  for (int kt = 0; kt < K_TOT; kt += BK) {
#pragma unroll
    for (int i = 0; i < 4; ++i) {
      gload16(gA[i] + kt, As + loff[i]);
      gload16(gB[i] + kt, Bs + loff[i]);
    }
    __syncthreads();  // vmcnt(0): staged data visible

    {
      bf16x8 af[4], bfr[4];
#pragma unroll
      for (int mi = 0; mi < 4; ++mi)
        af[mi] = *reinterpret_cast<const bf16x8*>(Asb + aoff0[mi]);
#pragma unroll
      for (int ni = 0; ni < 4; ++ni)
        bfr[ni] = *reinterpret_cast<const bf16x8*>(Bsb + boff0[ni]);
#pragma unroll
      for (int mi = 0; mi < 4; ++mi)
#pragma unroll
        for (int ni = 0; ni < 4; ++ni)
          acc[mi][ni] = __builtin_amdgcn_mfma_f32_16x16x32_bf16(
              af[mi], bfr[ni], acc[mi][ni], 0, 0, 0);
#pragma unroll
      for (int mi = 0; mi < 4; ++mi)
        af[mi] = *reinterpret_cast<const bf16x8*>(Asb + aoff1[mi]);
#pragma unroll
      for (int ni = 0; ni < 4; ++ni)
        bfr[ni] = *reinterpret_cast<const bf16x8*>(Bsb + boff1[ni]);
#pragma unroll
      for (int mi = 0; mi < 4; ++mi)
#pragma unroll
        for (int ni = 0; ni < 4; ++ni)
          acc[mi][ni] = __builtin_amdgcn_mfma_f32_16x16x32_bf16(
              af[mi], bfr[ni], acc[mi][ni], 0, 0, 0);
    }
    __syncthreads();  // all waves done reading before next stage
  }

  // ---------------- epilogue: + bias + inter @ B[slot] ----------------
  const int slot = idx[m0 >> 11];            // uniform per block (128 | 2048)
  const float* __restrict__ Bmat = loraB + (size_t)slot * RANK * N_TOT;

#pragma unroll
  for (int ni = 0; ni < 4; ++ni) {
    const int gn = n0 + wc * 64 + ni * 16 + (lane & 15);
    const float bv = bias[gn];
    float bc[RANK];
#pragma unroll
    for (int q = 0; q < RANK; ++q) bc[q] = Bmat[q * N_TOT + gn];
#pragma unroll
    for (int mi = 0; mi < 4; ++mi) {
      const int gmb = m0 + wr * 64 + mi * 16 + ((lane >> 4) << 2);
#pragma unroll
      for (int r = 0; r < 4; ++r) {
        const int gm = gmb + r;
        const float* __restrict__ iv = inter + (size_t)gm * RANK;
        float lora = 0.f;
#pragma unroll
        for (int q = 0; q < RANK; ++q) lora += iv[q] * bc[q];
        out[(size_t)gm * N_TOT + gn] = acc[mi][ni][r] + bv + lora;
      }
    }
  }
}

// ---------------- host launcher ----------------
extern "C" void kernel_launch(void* const* d_in, const int* in_sizes, int n_in,
                              void* d_out, int out_size, void* d_ws, size_t ws_size,
                              hipStream_t stream) {
  const float* x     = (const float*)d_in[0];  // [8,2048,4096]
  const float* w     = (const float*)d_in[1];  // [4096,4096]
  const float* bias  = (const float*)d_in[2];  // [4096]
  const float* loraA = (const float*)d_in[3];  // [32,4096,16]
  const float* loraB = (const float*)d_in[4];  // [32,16,4096]
  const int*   idx   = (const int*)d_in[5];    // [8]
  float* out = (float*)d_out;

  char* ws = (char*)d_ws;
  unsigned short* xb = (unsigned short*)ws;                       // 134,217,728 B
  unsigned short* wbuf = (unsigned short*)(ws + 134217728);       //  33,554,432 B
  float* inter = (float*)(ws + 134217728 + 33554432);             //   1,048,576 B

  fused_xcvt_inter_kernel<<<M_TOT / 16, 256, 0, stream>>>(x, loraA, idx, xb, inter);
  cvt_bf16_kernel<<<1024, 256, 0, stream>>>(w, wbuf, N_TOT * K_TOT / 4);
  gemm_fused_kernel<<<(M_TOT / BM) * (N_TOT / BN), 256, 0, stream>>>(
      xb, wbuf, bias, inter, loraB, idx, out);
}

// Round 4
// 1014.359 us; speedup vs baseline: 1.8028x; 1.3876x over previous
//
#include <hip/hip_runtime.h>
#include <hip/hip_bf16.h>

// MultiLoRALinear: out = x@W.T + bias + (x @ A[idx]) @ B[idx]
// M=16384, K=4096, N=4096, rank 16.
//
// R4: GEMM ported to the 256x256 deep-pipelined 8-phase structure (T3+T4+T5):
//  - BK=32, 4-deep LDS ring buffer (4 x 32KiB = 128KiB). Tile t reads buf[t&3],
//    stages tile t+3 into buf[(t+3)&3] (freed at end of tile t-1 -> race-free).
//  - Counted s_waitcnt vmcnt(8) once per K-tile (never 0 in steady state);
//    raw s_barrier (no __syncthreads -> no implicit vmcnt(0) drain).
//  - Per phase: {ds_read 8|4 x b128; stage 2 x global_load_lds; barrier;
//    lgkmcnt(0)+sched_barrier; setprio(1); 16 MFMA; setprio(0); barrier}.
//  - LDS swizzle for 64B rows: phys_slot = slot ^ ((row>>1)&3); each 8-lane
//    b128 group covers all 32 banks exactly once. Source pre-permuted (m173).
//  - XCD-aware block swizzle (1024 wgs % 8 == 0, bijective).

#define M_TOT 16384
#define K_TOT 4096
#define N_TOT 4096
#define RANK 16
#define NT 128   // K_TOT / 32 K-tiles

typedef __attribute__((ext_vector_type(8))) short bf16x8;
typedef __attribute__((ext_vector_type(4))) float f32x4;

// ---------------- fp32 -> bf16 (round-to-nearest-even) ----------------
__device__ __forceinline__ unsigned short f2bf(float f) {
  unsigned int u = __builtin_bit_cast(unsigned int, f);
  u += 0x7fffu + ((u >> 16) & 1u);
  return (unsigned short)(u >> 16);
}

__global__ void cvt_bf16_kernel(const float* __restrict__ src,
                                unsigned short* __restrict__ dst, int n4) {
  int i = blockIdx.x * blockDim.x + threadIdx.x;
  const int stride = gridDim.x * blockDim.x;
  for (; i < n4; i += stride) {
    const float4 v = reinterpret_cast<const float4*>(src)[i];
    ushort4 o;
    o.x = f2bf(v.x); o.y = f2bf(v.y); o.z = f2bf(v.z); o.w = f2bf(v.w);
    reinterpret_cast<ushort4*>(dst)[i] = o;
  }
}

// ------- fused: xb = bf16(x); inter = x @ A[slot]  (16 rows per block) -------
__global__ __launch_bounds__(256) void fused_xcvt_inter_kernel(
    const float* __restrict__ x,
    const float* __restrict__ loraA,
    const int* __restrict__ idx,
    unsigned short* __restrict__ xb,
    float* __restrict__ inter) {
  const int tid = threadIdx.x;
  const int row = blockIdx.x * 16 + (tid >> 4);
  const int p = tid & 15;
  const int slot = idx[row >> 11];
  const float* __restrict__ A = loraA + (size_t)slot * K_TOT * RANK;
  const float* __restrict__ xr = x + (size_t)row * K_TOT;
  unsigned short* __restrict__ xbr = xb + (size_t)row * K_TOT;

  float acc[RANK];
#pragma unroll
  for (int r = 0; r < RANK; ++r) acc[r] = 0.f;

  for (int i = 0; i < 64; ++i) {
    const int k = p * 4 + i * 64;
    const float4 xv = *reinterpret_cast<const float4*>(xr + k);
    ushort4 o;
    o.x = f2bf(xv.x); o.y = f2bf(xv.y); o.z = f2bf(xv.z); o.w = f2bf(xv.w);
    *reinterpret_cast<ushort4*>(xbr + k) = o;
    const float xe[4] = {xv.x, xv.y, xv.z, xv.w};
#pragma unroll
    for (int j = 0; j < 4; ++j) {
      const float4* Ar = reinterpret_cast<const float4*>(A + (size_t)(k + j) * RANK);
      const float4 a0 = Ar[0], a1 = Ar[1], a2 = Ar[2], a3 = Ar[3];
      const float xs = xe[j];
      acc[0]  += xs * a0.x;  acc[1]  += xs * a0.y;  acc[2]  += xs * a0.z;  acc[3]  += xs * a0.w;
      acc[4]  += xs * a1.x;  acc[5]  += xs * a1.y;  acc[6]  += xs * a1.z;  acc[7]  += xs * a1.w;
      acc[8]  += xs * a2.x;  acc[9]  += xs * a2.y;  acc[10] += xs * a2.z;  acc[11] += xs * a2.w;
      acc[12] += xs * a3.x;  acc[13] += xs * a3.y;  acc[14] += xs * a3.z;  acc[15] += xs * a3.w;
    }
  }
#pragma unroll
  for (int r = 0; r < RANK; ++r) {
    float v = acc[r];
    v += __shfl_xor(v, 1);
    v += __shfl_xor(v, 2);
    v += __shfl_xor(v, 4);
    v += __shfl_xor(v, 8);
    acc[r] = v;
  }
  if (p == 0) {
    float4* op = reinterpret_cast<float4*>(inter + (size_t)row * RANK);
    op[0] = make_float4(acc[0], acc[1], acc[2], acc[3]);
    op[1] = make_float4(acc[4], acc[5], acc[6], acc[7]);
    op[2] = make_float4(acc[8], acc[9], acc[10], acc[11]);
    op[3] = make_float4(acc[12], acc[13], acc[14], acc[15]);
  }
}

// ---------------- deep-pipelined 256x256 GEMM ----------------
__device__ __forceinline__ void gload16(const void* g, void* l) {
  __builtin_amdgcn_global_load_lds(
      (const __attribute__((address_space(1))) unsigned int*)g,
      (__attribute__((address_space(3))) unsigned int*)l, 16, 0, 0);
}

#define GBARRIER() asm volatile("s_barrier" ::: "memory")
#define WAIT_LGKM0()                                   \
  do {                                                 \
    asm volatile("s_waitcnt lgkmcnt(0)" ::: "memory"); \
    __builtin_amdgcn_sched_barrier(0);                 \
  } while (0)

__global__ __launch_bounds__(512, 2) void gemm_fused_kernel(
    const unsigned short* __restrict__ xb,   // [M][K] bf16
    const unsigned short* __restrict__ wb,   // [N][K] bf16
    const float* __restrict__ bias,          // [N]
    const float* __restrict__ inter,         // [M][RANK] f32
    const float* __restrict__ loraB,         // [32][RANK][N] f32
    const int* __restrict__ idx,             // [8]
    float* __restrict__ out) {               // [M][N] f32
  // 4 ring buffers x (A: 8192 shorts = 256x32, B: 8192 shorts) = 128 KiB
  __shared__ unsigned short lds[4][16384];
  char* ldsB = (char*)&lds[0][0];

  const int tid = threadIdx.x;
  const int lane = tid & 63;
  const int wv = tid >> 6;   // 0..7
  const int wr = wv >> 2;    // 0..1 (M half)
  const int wc = wv & 3;     // 0..3 (N quarter)

  // XCD-aware bijective swizzle: 1024 wgs, 8 XCDs, 128 per chunk
  const int bid = ((blockIdx.x & 7) << 7) | (blockIdx.x >> 3);
  const int m0 = (bid >> 4) << 8;   // 64 M-panels
  const int n0 = (bid & 15) << 8;   // 16 N-panels

  // ---- staging source (pre-permuted by the LDS swizzle involution) ----
  const int srow = tid >> 2;                        // 0..127
  const int sslot = (tid & 3) ^ ((srow >> 1) & 3);  // 16B slot within 64B row
  const unsigned short* xs0 = xb + (size_t)(m0 + srow) * K_TOT + sslot * 8;
  const unsigned short* xs1 = xs0 + (size_t)128 * K_TOT;
  const unsigned short* ws0 = wb + (size_t)(n0 + srow) * K_TOT + sslot * 8;
  const unsigned short* ws1 = ws0 + (size_t)128 * K_TOT;
  const int stgoff = wv << 10;  // wave-uniform LDS byte offset within region

#define STAGE_A(t)                                                  \
  do {                                                              \
    const int _bo = (((t) & 3) << 15);                              \
    gload16(xs0 + (size_t)(t) * 32, ldsB + _bo + stgoff);           \
    gload16(xs1 + (size_t)(t) * 32, ldsB + _bo + 8192 + stgoff);    \
  } while (0)
#define STAGE_B(t)                                                  \
  do {                                                              \
    const int _bo = (((t) & 3) << 15);                              \
    gload16(ws0 + (size_t)(t) * 32, ldsB + _bo + 16384 + stgoff);   \
    gload16(ws1 + (size_t)(t) * 32, ldsB + _bo + 24576 + stgoff);   \
  } while (0)

  // ---- ds_read per-lane byte offsets (buffer-relative, swizzled) ----
  const int rswz = ((lane & 15) >> 1) & 3;
  const int pslot = ((lane >> 4) ^ rswz) << 4;
  const int aoff = (wr * 128 + (lane & 15)) * 64 + pslot;
  const int boff = 16384 + (wc * 64 + (lane & 15)) * 64 + pslot;

  f32x4 acc[8][4];
#pragma unroll
  for (int i = 0; i < 8; ++i)
#pragma unroll
    for (int j = 0; j < 4; ++j) acc[i][j] = (f32x4){0.f, 0.f, 0.f, 0.f};

  // ---- prologue: stage tiles 0,1,2; wait for tile 0 (4 oldest of 12) ----
  STAGE_A(0); STAGE_B(0);
  STAGE_A(1); STAGE_B(1);
  STAGE_A(2); STAGE_B(2);
  asm volatile("s_waitcnt vmcnt(8)" ::: "memory");
  GBARRIER();

#pragma unroll 1
  for (int t = 0; t < NT; ++t) {
    const char* Ab = ldsB + ((t & 3) << 15) + aoff;
    const char* Bb = ldsB + ((t & 3) << 15) + boff;
    bf16x8 afrag[4], bfrag[4];

    // ---------------- phase 1: acc[0..3][0..3] ----------------
#pragma unroll
    for (int nf = 0; nf < 4; ++nf)
      bfrag[nf] = *reinterpret_cast<const bf16x8*>(Bb + nf * 1024);
#pragma unroll
    for (int mf = 0; mf < 4; ++mf)
      afrag[mf] = *reinterpret_cast<const bf16x8*>(Ab + mf * 1024);
    if (t < NT - 3) STAGE_A(t + 3);
    GBARRIER();
    WAIT_LGKM0();
    __builtin_amdgcn_s_setprio(1);
#pragma unroll
    for (int mf = 0; mf < 4; ++mf)
#pragma unroll
      for (int nf = 0; nf < 4; ++nf)
        acc[mf][nf] = __builtin_amdgcn_mfma_f32_16x16x32_bf16(
            afrag[mf], bfrag[nf], acc[mf][nf], 0, 0, 0);
    __builtin_amdgcn_s_setprio(0);
    GBARRIER();

    // ---------------- phase 2: acc[4..7][0..3] ----------------
#pragma unroll
    for (int mf = 0; mf < 4; ++mf)
      afrag[mf] = *reinterpret_cast<const bf16x8*>(Ab + (4 + mf) * 1024);
    if (t < NT - 3) STAGE_B(t + 3);
    GBARRIER();
    WAIT_LGKM0();
    __builtin_amdgcn_s_setprio(1);
#pragma unroll
    for (int mf = 0; mf < 4; ++mf)
#pragma unroll
      for (int nf = 0; nf < 4; ++nf)
        acc[4 + mf][nf] = __builtin_amdgcn_mfma_f32_16x16x32_bf16(
            afrag[mf], bfrag[nf], acc[4 + mf][nf], 0, 0, 0);
    __builtin_amdgcn_s_setprio(0);
    // tile boundary: guarantee tile t+1 resident (4 oldest of <=12 in flight)
    if (t < NT - 3) {
      asm volatile("s_waitcnt vmcnt(8)" ::: "memory");
    } else {
      asm volatile("s_waitcnt vmcnt(0)" ::: "memory");
    }
    GBARRIER();
  }

  // ---------------- epilogue: + bias + inter @ B[slot] ----------------
  const int slot = idx[m0 >> 11];  // block spans one batch (256 | 2048)
  const float* __restrict__ Bmat = loraB + (size_t)slot * RANK * N_TOT;
  const int gn0 = n0 + wc * 64 + (lane & 15);

  float bcv[4][RANK];
  float bv[4];
#pragma unroll
  for (int nf = 0; nf < 4; ++nf) {
    const int gn = gn0 + nf * 16;
    bv[nf] = bias[gn];
#pragma unroll
    for (int q = 0; q < RANK; ++q) bcv[nf][q] = Bmat[q * N_TOT + gn];
  }
#pragma unroll
  for (int mf = 0; mf < 8; ++mf) {
    const int gmb = m0 + wr * 128 + mf * 16 + ((lane >> 4) << 2);
#pragma unroll
    for (int r = 0; r < 4; ++r) {
      const int gm = gmb + r;
      const float4* ivp = reinterpret_cast<const float4*>(inter + (size_t)gm * RANK);
      const float4 iv0 = ivp[0], iv1 = ivp[1], iv2 = ivp[2], iv3 = ivp[3];
      float* orow = out + (size_t)gm * N_TOT;
#pragma unroll
      for (int nf = 0; nf < 4; ++nf) {
        float lora = iv0.x * bcv[nf][0] + iv0.y * bcv[nf][1] +
                     iv0.z * bcv[nf][2] + iv0.w * bcv[nf][3] +
                     iv1.x * bcv[nf][4] + iv1.y * bcv[nf][5] +
                     iv1.z * bcv[nf][6] + iv1.w * bcv[nf][7] +
                     iv2.x * bcv[nf][8] + iv2.y * bcv[nf][9] +
                     iv2.z * bcv[nf][10] + iv2.w * bcv[nf][11] +
                     iv3.x * bcv[nf][12] + iv3.y * bcv[nf][13] +
                     iv3.z * bcv[nf][14] + iv3.w * bcv[nf][15];
        orow[gn0 + nf * 16] = acc[mf][nf][r] + bv[nf] + lora;
      }
    }
  }
#undef STAGE_A
#undef STAGE_B
}

// ---------------- host launcher ----------------
extern "C" void kernel_launch(void* const* d_in, const int* in_sizes, int n_in,
                              void* d_out, int out_size, void* d_ws, size_t ws_size,
                              hipStream_t stream) {
  const float* x     = (const float*)d_in[0];  // [8,2048,4096]
  const float* w     = (const float*)d_in[1];  // [4096,4096]
  const float* bias  = (const float*)d_in[2];  // [4096]
  const float* loraA = (const float*)d_in[3];  // [32,4096,16]
  const float* loraB = (const float*)d_in[4];  // [32,16,4096]
  const int*   idx   = (const int*)d_in[5];    // [8]
  float* out = (float*)d_out;

  char* ws = (char*)d_ws;
  unsigned short* xb   = (unsigned short*)ws;                  // 134,217,728 B
  unsigned short* wbuf = (unsigned short*)(ws + 134217728);    //  33,554,432 B
  float* inter = (float*)(ws + 134217728 + 33554432);          //   1,048,576 B

  fused_xcvt_inter_kernel<<<M_TOT / 16, 256, 0, stream>>>(x, loraA, idx, xb, inter);
  cvt_bf16_kernel<<<1024, 256, 0, stream>>>(w, wbuf, N_TOT * K_TOT / 4);
  gemm_fused_kernel<<<(M_TOT / 256) * (N_TOT / 256), 512, 0, stream>>>(
      xb, wbuf, bias, inter, loraB, idx, out);
}